// Round 6
// baseline (672.194 us; speedup 1.0000x reference)
//
#include <hip/hip_runtime.h>
#include <stdint.h>

// Problem constants
#define BB   2
#define SS   2048
#define HID  2048
#define NHQ  16
#define NKV  8
#define DD   128
// QKV fused row layout: [q: 16*128 | k: 8*128 | v: 8*128] = 4096 bf16 per (b,s)
#define QKVW 4096

typedef __bf16 v8bf   __attribute__((ext_vector_type(8)));
typedef float  f32x4  __attribute__((ext_vector_type(4)));
typedef float  f32x16 __attribute__((ext_vector_type(16)));

__device__ __forceinline__ float bf2f(ushort u) {
    union { unsigned int i; float f; } x; x.i = ((unsigned int)u) << 16; return x.f;
}
__device__ __forceinline__ ushort f2bf(float f) {
    union { float f; unsigned int i; } x; x.f = f;
    unsigned int i = x.i;
    return (ushort)((i + 0x7fffu + ((i >> 16) & 1u)) >> 16); // RNE, finite inputs
}
__device__ __forceinline__ v8bf as_bf8(uint4 u) { return __builtin_bit_cast(v8bf, u); }

__device__ __forceinline__ void store_el(float* p, float v)  { *p = v; }
__device__ __forceinline__ void store_el(ushort* p, float v) { *p = f2bf(v); }

// async global->LDS, 16B per lane; lds must be wave-uniform-base + lane*16
__device__ __forceinline__ void gll16(const ushort* g, ushort* l) {
    __builtin_amdgcn_global_load_lds(
        (const __attribute__((address_space(1))) void*)g,
        (__attribute__((address_space(3))) void*)l, 16, 0, 0);
}

// ------------------------------------------------------------- fused prep kernel
#define PREP_CAST   8192
#define PREP_WQ     (PREP_CAST)              // 64x64 tiles
#define PREP_WK     (PREP_WQ + 4096)         // 32x64
#define PREP_WV     (PREP_WK + 2048)
#define PREP_WO     (PREP_WV + 2048)         // 64x64
#define PREP_TOTAL  (PREP_WO + 4096)

__device__ __forceinline__ void tcast_body(
    const float* __restrict__ in, ushort* __restrict__ out,
    int K, int N, int bx, int by, int t)
{
    __shared__ float tile[32][33];
    int n0 = bx * 32, k0 = by * 32;
    int tx = t & 31, ty = t >> 5; // 32 x 8
#pragma unroll
    for (int i = 0; i < 32; i += 8)
        tile[ty + i][tx] = in[(size_t)(k0 + ty + i) * N + n0 + tx];
    __syncthreads();
#pragma unroll
    for (int i = 0; i < 32; i += 8)
        out[(size_t)(n0 + ty + i) * K + k0 + tx] = f2bf(tile[tx][ty + i]);
}

__global__ __launch_bounds__(256) void prep(
    const float* __restrict__ X,  const float* __restrict__ wq,
    const float* __restrict__ wk, const float* __restrict__ wv,
    const float* __restrict__ wo,
    ushort* __restrict__ Xb, ushort* __restrict__ WqkvT, ushort* __restrict__ Wot)
{
    int bid = blockIdx.x, t = threadIdx.x;
    if (bid < PREP_CAST) {
        int i = (bid * 256 + t) * 4;
        float4 v = *(const float4*)&X[i];
        ushort4 o = { f2bf(v.x), f2bf(v.y), f2bf(v.z), f2bf(v.w) };
        *(ushort4*)&Xb[i] = o;
    } else if (bid < PREP_WK) {
        int l = bid - PREP_WQ;
        tcast_body(wq, WqkvT, 2048, 2048, l & 63, l >> 6, t);
    } else if (bid < PREP_WV) {
        int l = bid - PREP_WK;
        tcast_body(wk, WqkvT + (size_t)2048 * 2048, 2048, 1024, l & 31, l >> 5, t);
    } else if (bid < PREP_WO) {
        int l = bid - PREP_WV;
        tcast_body(wv, WqkvT + (size_t)3072 * 2048, 2048, 1024, l & 31, l >> 5, t);
    } else {
        int l = bid - PREP_WO;
        tcast_body(wo, Wot, 2048, 2048, l & 63, l >> 6, t);
    }
}

// ---------------------------------------------------------------- GEMM: C = A @ Bt^T
// R4 (best-known) m97 structure: 128x128 block, BK=32, unpadded LDS, gll width-16,
// two barriers per K-step. Pipelining attempts regressed (R5): keep this form.
template <typename OutT>
__global__ __launch_bounds__(256) void gemm_bt(
    const ushort* __restrict__ A, const ushort* __restrict__ Bt,
    OutT* __restrict__ C, int M, int N, int K)
{
    __shared__ __align__(16) ushort As[128 * 32];
    __shared__ __align__(16) ushort Bs[128 * 32];
    const int t = threadIdx.x;
    const int lane = t & 63, wave = t >> 6;
    const int quad = lane >> 4, l15 = lane & 15;
    const int m0 = blockIdx.y * 128, n0 = blockIdx.x * 128;
    const int wm = (wave >> 1) * 64, wn = (wave & 1) * 64;

    const f32x4 zv = {0.f, 0.f, 0.f, 0.f};
    f32x4 acc[4][4];
#pragma unroll
    for (int i = 0; i < 4; i++)
#pragma unroll
        for (int j = 0; j < 4; j++) acc[i][j] = zv;

    const int srow = t >> 2, sc8 = (t & 3) << 3;

    for (int k0 = 0; k0 < K; k0 += 32) {
        __syncthreads();
#pragma unroll
        for (int i = 0; i < 2; i++) {
            gll16(&A[(size_t)(m0 + srow + i * 64) * K + k0 + sc8], &As[(i * 256 + t) * 8]);
            gll16(&Bt[(size_t)(n0 + srow + i * 64) * K + k0 + sc8], &Bs[(i * 256 + t) * 8]);
        }
        __syncthreads();
        uint4 af[4], bf[4];
#pragma unroll
        for (int i = 0; i < 4; i++)
            af[i] = *(const uint4*)&As[(wm + i * 16 + l15) * 32 + quad * 8];
#pragma unroll
        for (int i = 0; i < 4; i++)
            bf[i] = *(const uint4*)&Bs[(wn + i * 16 + l15) * 32 + quad * 8];
#pragma unroll
        for (int mi = 0; mi < 4; mi++)
#pragma unroll
            for (int ni = 0; ni < 4; ni++)
                acc[mi][ni] = __builtin_amdgcn_mfma_f32_16x16x32_bf16(
                    as_bf8(af[mi]), as_bf8(bf[ni]), acc[mi][ni], 0, 0, 0);
    }
#pragma unroll
    for (int mi = 0; mi < 4; mi++)
#pragma unroll
        for (int ni = 0; ni < 4; ni++)
#pragma unroll
            for (int r = 0; r < 4; r++) {
                int row = m0 + wm + mi * 16 + quad * 4 + r;
                int col = n0 + wn + ni * 16 + l15;
                store_el(&C[(size_t)row * N + col], acc[mi][ni][r]);
            }
}

// ------------------------------------------- per-head RMSNorm + RoPE, in place on QKV
__global__ __launch_bounds__(256) void norm_rope(
    ushort* __restrict__ qkv, const float* __restrict__ qw, const float* __restrict__ kw)
{
    int row = blockIdx.x;            // b*S + s
    int s = row & (SS - 1);
    int lane = threadIdx.x & 63, wave = threadIdx.x >> 6;
    int l = lane & 31, hsel = lane >> 5;
    float d0 = (float)(2 * l), d1 = d0 + 1.0f;
    float inv0 = expf(-d0 * (1.0f / 64.0f) * 9.210340371976184f);
    float inv1 = expf(-d1 * (1.0f / 64.0f) * 9.210340371976184f);
    float c0, s0, c1, s1;
    sincosf((float)s * inv0, &s0, &c0);
    sincosf((float)s * inv1, &s1, &c1);
    float qw0 = qw[2 * l], qw1 = qw[2 * l + 1], qy0 = qw[2 * l + 64], qy1 = qw[2 * l + 65];
    float kw0 = kw[2 * l], kw1 = kw[2 * l + 1], ky0 = kw[2 * l + 64], ky1 = kw[2 * l + 65];

#pragma unroll
    for (int pass = 0; pass < 3; pass++) {
        int h = pass * 8 + wave * 2 + hsel;
        ushort* p = qkv + (size_t)row * QKVW + h * 128;
        unsigned int ulo = *(const unsigned int*)&p[2 * l];
        unsigned int uhi = *(const unsigned int*)&p[2 * l + 64];
        float x0 = bf2f((ushort)ulo), x1 = bf2f((ushort)(ulo >> 16));
        float y0 = bf2f((ushort)uhi), y1 = bf2f((ushort)(uhi >> 16));
        float ssum = x0 * x0 + x1 * x1 + y0 * y0 + y1 * y1;
#pragma unroll
        for (int xm = 1; xm < 32; xm <<= 1) ssum += __shfl_xor(ssum, xm, 64);
        float r = rsqrtf(ssum * (1.0f / 128.0f) + 1e-6f);
        bool isq = (h < 16);
        float w0 = isq ? qw0 : kw0, w1 = isq ? qw1 : kw1;
        float v0 = isq ? qy0 : ky0, v1 = isq ? qy1 : ky1;
        float sc = isq ? 0.08838834764831845f : 1.0f; // 1/sqrt(128) folded into q
        float nx0 = w0 * (x0 * r), nx1 = w1 * (x1 * r);
        float ny0 = v0 * (y0 * r), ny1 = v1 * (y1 * r);
        float ox0 = (nx0 * c0 - ny0 * s0) * sc, ox1 = (nx1 * c1 - ny1 * s1) * sc;
        float oy0 = (ny0 * c0 + nx0 * s0) * sc, oy1 = (ny1 * c1 + nx1 * s1) * sc;
        *(unsigned int*)&p[2 * l]      = (unsigned int)f2bf(ox0) | ((unsigned int)f2bf(ox1) << 16);
        *(unsigned int*)&p[2 * l + 64] = (unsigned int)f2bf(oy0) | ((unsigned int)f2bf(oy1) << 16);
    }
}

// ---------------------------------------------------------------- flash attention
// R4 structure (2 barriers, single-buffered Ks/Vt, 48KB LDS) + K-split x2:
// blockIdx.z = b*2 + ks; each block does keys [ks*1024, ks*1024+1024) (16 tiles).
// Fixed-max softmax => halves combine exactly via (N0+N1)/(L0+L1).
// Outputs: bf16 unnormalized numerator partials + fp32 row-sum partials.
// pi key-permutation (kappa = 2*l31 + nt) keeps P-stores packed b32.
__global__ __launch_bounds__(256, 3) void flash_attn(
    const ushort* __restrict__ qkv, const float* __restrict__ mask,
    ushort* __restrict__ Num0, ushort* __restrict__ Num1, float* __restrict__ Lbuf)
{
    __shared__ __align__(16) ushort Ks[64 * 128];   // [key][dchunk ^ (key&15)]
    __shared__ __align__(16) ushort Vt[128 * 64];   // [d][kchunk ^ (d&7)] kappa-order
    __shared__ __align__(16) ushort Ps[4 * 32 * 64];// per-wave [qrow][kchunk ^ (qrow&7)]
    const int t = threadIdx.x;
    const int lane = t & 63, wave = t >> 6;
    const int l31 = lane & 31, half = lane >> 5;
    const int b = blockIdx.z >> 1, ks = blockIdx.z & 1;
    const int h = blockIdx.y, q0 = blockIdx.x * 128;
    const int kh = h >> 1; // GQA
    const int kbase = ks << 10;
    ushort* __restrict__ Num = ks ? Num1 : Num0;

    // Q A-frags for 32x32x16: A[m=l31][k=half*8+j], kt=0..7 over d=128
    uint4 aq[8];
    {
        const ushort* qp = qkv + ((size_t)(b * SS + q0 + wave * 32 + l31)) * QKVW + h * 128 + half * 8;
#pragma unroll
        for (int kt = 0; kt < 8; kt++) aq[kt] = *(const uint4*)&qp[kt * 16];
    }
    f32x16 acc_o[4];
#pragma unroll
    for (int i = 0; i < 4; i++)
#pragma unroll
        for (int r = 0; r < 16; r++) acc_o[i][r] = 0.f;
    float l_part[16];
#pragma unroll
    for (int r = 0; r < 16; r++) l_part[r] = 0.f;

    const ushort* Kg = qkv + (size_t)b * SS * QKVW + 2048 + kh * 128;
    const ushort* Vg = qkv + (size_t)b * SS * QKVW + 3072 + kh * 128;

    const int vp = t & 31, vdc = t >> 5; // V staging: keys (vp, vp+32), d-group vdc
    uint4 vreg[4];

#define LOAD_V(K0) do {                                                               \
    _Pragma("unroll")                                                                 \
    for (int pass = 0; pass < 2; pass++) {                                            \
        int d0 = (vdc + pass * 8) * 8;                                                \
        vreg[pass * 2 + 0] = *(const uint4*)&Vg[(size_t)((K0) + vp) * QKVW + d0];     \
        vreg[pass * 2 + 1] = *(const uint4*)&Vg[(size_t)((K0) + 32 + vp) * QKVW + d0];\
    } } while (0)

    LOAD_V(kbase);
    const int pwb = wave * 2048; // Ps wave base (32*64)

    for (int i = 0; i < 16; i++) {
        const int k0 = kbase + i * 64;
        __syncthreads(); // prior tile's LDS reads done
        // K tile: async global->LDS; slot (row,cp) holds logical chunk cp^(row&15)
#pragma unroll
        for (int ii = 0; ii < 4; ii++) {
            int chunk = ii * 256 + t;
            int row = chunk >> 4, cpz = chunk & 15;
            int cl = cpz ^ (row & 15);
            gll16(&Kg[(size_t)(k0 + row) * QKVW + cl * 8], &Ks[chunk * 8]);
        }
        // V tile: transpose from vreg; kappa pairs (vp, vp+32) pack one b32
#pragma unroll
        for (int pass = 0; pass < 2; pass++) {
            const ushort* pa = (const ushort*)&vreg[pass * 2 + 0];
            const ushort* pb = (const ushort*)&vreg[pass * 2 + 1];
            int d0 = (vdc + pass * 8) * 8;
#pragma unroll
            for (int j = 0; j < 8; j++) {
                int d = d0 + j;
                int cp = (vp >> 2) ^ (d & 7);
                unsigned int val = (unsigned int)pa[j] | ((unsigned int)pb[j] << 16);
                *(unsigned int*)&Vt[d * 64 + cp * 8 + 2 * (vp & 3)] = val;
            }
        }
        __syncthreads(); // staging visible, DMA drained
        if (i + 1 < 16) LOAD_V(k0 + 64); // next V in flight during compute

        // scores: S = Q K^T, 2 col-tiles of 32 keys, 8 d-steps of 16
        f32x16 sc[2];
#pragma unroll
        for (int nt = 0; nt < 2; nt++) {
#pragma unroll
            for (int r = 0; r < 16; r++) sc[nt][r] = 0.f;
#pragma unroll
            for (int kt = 0; kt < 8; kt++) {
                int cp = (kt * 2 + half) ^ (l31 & 15);
                uint4 bk = *(const uint4*)&Ks[(nt * 32 + l31) * 128 + cp * 8];
                sc[nt] = __builtin_amdgcn_mfma_f32_32x32x16_bf16(
                    as_bf8(aq[kt]), as_bf8(bk), sc[nt], 0, 0, 0);
            }
        }
        // mask + exp + partial row sums
#pragma unroll
        for (int nt = 0; nt < 2; nt++) {
            float mv = mask[b * SS + k0 + nt * 32 + l31];
            float madd = (1.0f - mv) * -1e30f;
#pragma unroll
            for (int r = 0; r < 16; r++) {
                float pv = __expf(sc[nt][r] + madd);
                sc[nt][r] = pv;
                l_part[r] += pv;
            }
        }
        // P -> per-wave LDS, kappa-order: (nt=0,nt=1) pair packs into one b32
#pragma unroll
        for (int r = 0; r < 16; r++) {
            int prow = (r & 3) + 8 * (r >> 2) + 4 * half;
            int cp = (l31 >> 2) ^ (prow & 7);
            unsigned int pv2 = (unsigned int)f2bf(sc[0][r]) | ((unsigned int)f2bf(sc[1][r]) << 16);
            *(unsigned int*)&Ps[pwb + prow * 64 + cp * 8 + 2 * (l31 & 3)] = pv2;
        }
        // PV: A = P[32 q x 64 kappa], B = Vt[kappa x d], 4 k-steps, 4 d-tiles
#pragma unroll
        for (int kt2 = 0; kt2 < 4; kt2++) {
            int kc = kt2 * 2 + half;
            uint4 ap = *(const uint4*)&Ps[pwb + l31 * 64 + (kc ^ (l31 & 7)) * 8];
#pragma unroll
            for (int nt = 0; nt < 4; nt++) {
                int d = nt * 32 + l31;
                uint4 bv = *(const uint4*)&Vt[d * 64 + (kc ^ (l31 & 7)) * 8];
                acc_o[nt] = __builtin_amdgcn_mfma_f32_32x32x16_bf16(
                    as_bf8(ap), as_bf8(bv), acc_o[nt], 0, 0, 0);
            }
        }
    }
#undef LOAD_V
    // row-sum partials: reduce over 32-lane halves, write fp32 L
    float l_sum[16];
#pragma unroll
    for (int r = 0; r < 16; r++) {
        float s = l_part[r];
#pragma unroll
        for (int xm = 1; xm < 32; xm <<= 1) s += __shfl_xor(s, xm, 64);
        l_sum[r] = s;
    }
    if (l31 == 0) {
#pragma unroll
        for (int r = 0; r < 16; r++) {
            int prow = (r & 3) + 8 * (r >> 2) + 4 * half;
            Lbuf[((size_t)(ks * BB + b) * NHQ + h) * SS + q0 + wave * 32 + prow] = l_sum[r];
        }
    }
    // unnormalized numerator partials, bf16
#pragma unroll
    for (int nt = 0; nt < 4; nt++)
#pragma unroll
        for (int r = 0; r < 16; r++) {
            int prow = (r & 3) + 8 * (r >> 2) + 4 * half;
            int qrow = q0 + wave * 32 + prow;
            int d = nt * 32 + l31;
            Num[((size_t)(b * SS + qrow)) * (NHQ * DD) + h * 128 + d] = f2bf(acc_o[nt][r]);
        }
}

// ---------------------------------------------------------------- combine halves
// O = (N0 + N1) / (L0 + L1); 4 elems/thread (same head: 4-aligned within 128)
__global__ __launch_bounds__(256) void combine(
    const ushort* __restrict__ N0, const ushort* __restrict__ N1,
    const float* __restrict__ L, ushort* __restrict__ O)
{
    int idx = (blockIdx.x * 256 + threadIdx.x) * 4;
    int row = idx >> 11;        // b*SS + s
    int col = idx & 2047;
    int h = col >> 7;
    int b = row >> 11, s = row & (SS - 1);
    float l0 = L[((size_t)(b)*NHQ + h) * SS + s];
    float l1 = L[((size_t)(BB + b) * NHQ + h) * SS + s];
    float inv = 1.0f / (l0 + l1);
    uint2 a = *(const uint2*)&N0[idx];
    uint2 c = *(const uint2*)&N1[idx];
    ushort4 o;
    o.x = f2bf((bf2f((ushort)a.x)         + bf2f((ushort)c.x))         * inv);
    o.y = f2bf((bf2f((ushort)(a.x >> 16)) + bf2f((ushort)(c.x >> 16))) * inv);
    o.z = f2bf((bf2f((ushort)a.y)         + bf2f((ushort)c.y))         * inv);
    o.w = f2bf((bf2f((ushort)(a.y >> 16)) + bf2f((ushort)(c.y >> 16))) * inv);
    *(ushort4*)&O[idx] = o;
}

// ---------------------------------------------------------------- launch
extern "C" void kernel_launch(void* const* d_in, const int* in_sizes, int n_in,
                              void* d_out, int out_size, void* d_ws, size_t ws_size,
                              hipStream_t stream)
{
    const float* X    = (const float*)d_in[0];
    const float* mask = (const float*)d_in[1];
    const float* wq   = (const float*)d_in[2];
    const float* wk   = (const float*)d_in[3];
    const float* wv   = (const float*)d_in[4];
    const float* wo   = (const float*)d_in[5];
    const float* qnw  = (const float*)d_in[6];
    const float* knw  = (const float*)d_in[7];
    float* out = (float*)d_out;

    const size_t M = (size_t)BB * SS; // 4096
    ushort* Xb    = (ushort*)d_ws;                       // 4096x2048 (dead after gemm1 -> Num0)
    ushort* WqkvT = Xb    + M * HID;                     // 4096x2048 (dead after gemm1 -> Num1)
    ushort* Wot   = WqkvT + (size_t)4096 * HID;          // 2048x2048
    ushort* QKV   = Wot   + (size_t)2048 * 2048;         // 4096x4096
    ushort* Obuf  = QKV   + M * QKVW;                    // 4096x2048
    float*  Lbuf  = out;   // d_out as scratch for row-sum partials (overwritten by gemm2)

    prep<<<PREP_TOTAL, 256, 0, stream>>>(X, wq, wk, wv, wo, Xb, WqkvT, Wot);

    // fused QKV projection: (4096,2048) @ (4096,2048)^T -> (4096,4096)
    gemm_bt<ushort><<<dim3(4096 / 128, 4096 / 128), 256, 0, stream>>>(Xb, WqkvT, QKV, 4096, 4096, 2048);

    norm_rope<<<(int)M, 256, 0, stream>>>(QKV, qnw, knw);

    // flash with K-split x2; Num partials overwrite Xb/WqkvT (dead), L -> d_out scratch
    flash_attn<<<dim3(SS / 128, NHQ, BB * 2), 256, 0, stream>>>(QKV, mask, Xb, WqkvT, Lbuf);

    combine<<<(int)(M * HID / 4 / 256), 256, 0, stream>>>(Xb, WqkvT, Lbuf, Obuf);

    // out projection: (4096,2048) @ (2048,2048)^T -> fp32 d_out
    gemm_bt<float><<<dim3(2048 / 128, 4096 / 128), 256, 0, stream>>>(Obuf, Wot, out, 4096, 2048, 2048);
}